// Round 8
// baseline (4685.496 us; speedup 1.0000x reference)
//
#include <hip/hip_runtime.h>

#define NN 10000
#define BB 32
#define EE 40000
#define HH 4
#define DD 10
#define TT 10
#define FS 12          // padded feat row stride (48 B, 16-B aligned)
#define JJ 8           // edge slots per (n,b) handled per round
#define NEG 0.2f

#define NB   (NN*BB)          // 320000
#define NBT  (NN*BB*TT)       // 3200000
#define NBF  (NN*BB*FS)       // 3840000 padded feat elems

// ---------------- extract mu/sigma + regression heads ----------------
__global__ void extract_kernel(const float* __restrict__ x,
                               const float* __restrict__ wmu, const float* __restrict__ bmu,
                               const float* __restrict__ wsg, const float* __restrict__ bsg,
                               float* __restrict__ mu, float* __restrict__ sg,
                               float* __restrict__ regmu, float* __restrict__ regsg) {
    int i = blockIdx.x * blockDim.x + threadIdx.x;   // over N*B
    if (i >= NB) return;
    int n = i / BB, b = i % BB;
    float smu = 0.f, ssg = 0.f;
    float muv[TT], sgv[TT];
#pragma unroll
    for (int t = 0; t < TT; t++) {
        size_t xi = (((size_t)t * NN + n) * BB + b) * 3;
        float m = x[xi], s = x[xi + 1];
        muv[t] = m; sgv[t] = s;
        smu += m * wmu[t];
        ssg += s * wsg[t];
    }
#pragma unroll
    for (int t = 0; t < TT; t++) {
        mu[(size_t)i * FS + t] = muv[t];
        sg[(size_t)i * FS + t] = sgv[t];
    }
    regmu[i] = smu + bmu[0];
    regsg[i] = ssg + bsg[0];
}

// ---------------- CSR build ----------------
__global__ void deg_kernel(const int* __restrict__ dst, int* __restrict__ deg) {
    int e = blockIdx.x * blockDim.x + threadIdx.x;
    if (e < EE) atomicAdd(&deg[dst[e]], 1);
}

__global__ void csr8init_kernel(int* __restrict__ c8a, int* __restrict__ c8b) {
    int i = blockIdx.x * blockDim.x + threadIdx.x;   // NN*JJ
    if (i < NN * JJ) { int n = i >> 3; c8a[i] = n; c8b[i] = n; }
}

__global__ void scan_kernel(const int* __restrict__ deg, int* __restrict__ off) {
    __shared__ int sm[1024];
    __shared__ int carry_s;
    if (threadIdx.x == 0) { carry_s = 0; off[0] = 0; }
    __syncthreads();
    for (int base = 0; base < NN; base += 1024) {
        int i = base + (int)threadIdx.x;
        int v = (i < NN) ? deg[i] : 0;
        sm[threadIdx.x] = v;
        __syncthreads();
        for (int s = 1; s < 1024; s <<= 1) {
            int t = (threadIdx.x >= (unsigned)s) ? sm[threadIdx.x - s] : 0;
            __syncthreads();
            sm[threadIdx.x] += t;
            __syncthreads();
        }
        if (i < NN) off[i + 1] = carry_s + sm[threadIdx.x];
        __syncthreads();
        if (threadIdx.x == 0) carry_s += sm[1023];
        __syncthreads();
    }
}

__global__ void fill_kernel(const int* __restrict__ src, const int* __restrict__ dst,
                            const int* __restrict__ off, int* __restrict__ cursor,
                            int* __restrict__ csr_src, int* __restrict__ csr8) {
    int e = blockIdx.x * blockDim.x + threadIdx.x;
    if (e < EE) {
        int d = dst[e];
        int p = atomicAdd(&cursor[d], 1);
        int s = src[e];
        csr_src[off[d] + p] = s;
        if (p < JJ) csr8[d * JJ + p] = s;
    }
}

// ---------------- precompute vl/vr for all 8 GATs ----------------
// vbuf layout: 8 slots of [vl(H*T=40) | vr(40)];
__global__ void vpre_kernel(const float* __restrict__ fc0, const float* __restrict__ al0, const float* __restrict__ ar0,
                            const float* __restrict__ fc1, const float* __restrict__ al1, const float* __restrict__ ar1,
                            const float* __restrict__ fc2, const float* __restrict__ al2, const float* __restrict__ ar2,
                            const float* __restrict__ fc3, const float* __restrict__ al3, const float* __restrict__ ar3,
                            float* __restrict__ vbuf) {
    int j = threadIdx.x;                 // 0..319
    if (j >= 320) return;
    int g = j / 40, r = j % 40;
    int h = r / 10, t = r % 10;
    int which = g & 3, layer = g >> 2;
    const float* fc; const float* al; const float* ar;
    if (which == 0)      { fc = fc0; al = al0; ar = ar0; }
    else if (which == 1) { fc = fc1; al = al1; ar = ar1; }
    else if (which == 2) { fc = fc2; al = al2; ar = ar2; }
    else                 { fc = fc3; al = al3; ar = ar3; }
    fc += layer * (HH * DD * TT);
    al += layer * (HH * DD);
    ar += layer * (HH * DD);
    float vl = 0.f, vr = 0.f;
#pragma unroll
    for (int d = 0; d < DD; d++) {
        float w = fc[(h * DD + d) * TT + t];
        vl += al[h * DD + d] * w;
        vr += ar[h * DD + d] * w;
    }
    vbuf[g * 80 + r] = vl;
    vbuf[g * 80 + 40 + r] = vr;
}

// ---------------- quad-GAT, edge-parallel lanes ----------------
// r7 post-mortem: per-GAT time pinned ~130 us across 3 structures; both pipes
// idle -> serial dependent gather chain (off->csr->rows, ~4 round trips/wave)
// is the limiter. This version: wave = 2 (n,b) pairs; half-wave lanes =
// (h=0..3) x (edge slot j=0..7). Padded csr8[n][8] is addressable directly
// from n, so round 1 = {csr8, deg, off, self row} all independent, round 2 =
// all <=8 edge rows in parallel. 2 dependent rounds instead of ~4, 8x MLP.
// Aggregation via shfl_xor butterfly over j (masks 1,2,4), head-mean via
// masks 8,16. deg>8 (2.1% of nodes, Poisson-4) loops via the full CSR.
struct GatCfg {
    const float* f; const float* W; const float* v;
    const int* off; const int* csr; const int* csr8; const int* deg;
    float* g; float* stats;
};
struct GatCfg4 { GatCfg c[4]; };

#define LOAD_ROW(dst, q)                                        \
    {                                                           \
        float4 _r0 = *(const float4*)(q);                       \
        float4 _r1 = *(const float4*)((q) + 4);                 \
        float2 _r2 = *(const float2*)((q) + 8);                 \
        dst[0]=_r0.x; dst[1]=_r0.y; dst[2]=_r0.z; dst[3]=_r0.w; \
        dst[4]=_r1.x; dst[5]=_r1.y; dst[6]=_r1.z; dst[7]=_r1.w; \
        dst[8]=_r2.x; dst[9]=_r2.y;                             \
    }

template <bool STATS>
__global__ void __launch_bounds__(256)
gat4_kernel(GatCfg4 cfgs) {
    const GatCfg cfg = cfgs.c[blockIdx.y];
    __shared__ float sW[HH * DD * TT];      // 400
    __shared__ float sv[2 * HH * TT];       // 80: [vl(40) | vr(40)]
    for (int k = threadIdx.x; k < HH * DD * TT; k += blockDim.x) sW[k] = cfg.W[k];
    if (threadIdx.x < 2 * HH * TT) sv[threadIdx.x] = cfg.v[threadIdx.x];
    __syncthreads();

    const float* __restrict__ f = cfg.f;

    int lane = threadIdx.x & 63;
    int wv   = threadIdx.x >> 6;            // wave in block: 0..3
    int q    = lane >> 5;                   // which (n,b) of the pair
    int h    = (lane >> 3) & 3;             // head
    int j    = lane & 7;                    // edge slot
    int nb   = blockIdx.x * 8 + wv * 2 + q; // < NB (grid.x = NB/8)
    int b    = nb & 31, n = nb >> 5;

    // per-lane attention vectors for this head
    float vl[TT], vr[TT];
#pragma unroll
    for (int t = 0; t < TT; t++) {
        vl[t] = sv[h * TT + t];
        vr[t] = sv[HH * TT + h * TT + t];
    }

    // ---- round 1: csr8 slot, degree, off (for overflow), self row ----
    int c    = cfg.csr8[n * JJ + j];
    int dg   = cfg.deg[n];
    int offn = cfg.off[n];
    float fs[TT];
    LOAD_ROW(fs, f + (size_t)nb * FS);
    float er = 0.f;
#pragma unroll
    for (int t = 0; t < TT; t++) er += vr[t] * fs[t];

    // ---- round 2: all <=8 edge rows in parallel ----
    float acc[TT];
    float den;
    {
        const float* qa = f + (size_t)(c * BB + b) * FS;
        float fa[TT];
        LOAD_ROW(fa, qa);
        float el = 0.f;
#pragma unroll
        for (int t = 0; t < TT; t++) el += vl[t] * fa[t];
        float z = el + er; z = (z >= 0.f) ? z : NEG * z;
        float w = __expf(z);
        if (j >= dg) w = 0.f;
        den = w;
#pragma unroll
        for (int t = 0; t < TT; t++) acc[t] = w * fa[t];
    }
    // overflow rounds for deg > 8 (wave-uniform branch; ~2% of nodes)
    for (int base = JJ; base < dg; base += JJ) {
        int valid = (base + j) < dg;
        int idx = valid ? (offn + base + j) : offn;
        int s2 = cfg.csr[idx];
        const float* qa = f + (size_t)(s2 * BB + b) * FS;
        float fa[TT];
        LOAD_ROW(fa, qa);
        float el = 0.f;
#pragma unroll
        for (int t = 0; t < TT; t++) el += vl[t] * fa[t];
        float z = el + er; z = (z >= 0.f) ? z : NEG * z;
        float w = __expf(z);
        if (!valid) w = 0.f;
        den += w;
#pragma unroll
        for (int t = 0; t < TT; t++) acc[t] += w * fa[t];
    }

    // ---- butterfly reduce over edge slots j (lane bits 0-2) ----
#pragma unroll
    for (int m = 1; m <= 4; m <<= 1) {
        den += __shfl_xor(den, m, 64);
#pragma unroll
        for (int t = 0; t < TT; t++) acc[t] += __shfl_xor(acc[t], m, 64);
    }

    float rd = (dg > 0) ? (1.0f / den) : 0.f;

    // ---- epilogue: W_h rows d=j (and d=8+j for j<2), leaky, 0.25 ----
    float o1 = 0.f;
#pragma unroll
    for (int t = 0; t < TT; t++) o1 += sW[h * (DD * TT) + j * TT + t] * acc[t];
    o1 *= rd;
    o1 = (o1 >= 0.f) ? o1 : NEG * o1;
    o1 *= 0.25f;
    float o2 = 0.f;
    if (j < 2) {
#pragma unroll
        for (int t = 0; t < TT; t++) o2 += sW[h * (DD * TT) + (8 + j) * TT + t] * acc[t];
        o2 *= rd;
        o2 = (o2 >= 0.f) ? o2 : NEG * o2;
        o2 *= 0.25f;
    }
    // head-mean via butterfly over h (lane bits 3-4)
    o1 += __shfl_xor(o1, 8, 64);  o1 += __shfl_xor(o1, 16, 64);
    o2 += __shfl_xor(o2, 8, 64);  o2 += __shfl_xor(o2, 16, 64);

    float lsum = 0.f, lsq = 0.f;
    if (h == 0) {
        float* gp = cfg.g + (size_t)nb * DD;
        gp[j] = o1;
        if (j < 2) gp[8 + j] = o2;
        if (STATS) {
            lsum = o1 + ((j < 2) ? o2 : 0.f);
            lsq  = o1 * o1 + ((j < 2) ? o2 * o2 : 0.f);
        }
    }
    if (STATS) {
#pragma unroll
        for (int o = 32; o > 0; o >>= 1) {
            lsum += __shfl_down(lsum, o, 64);
            lsq  += __shfl_down(lsq, o, 64);
        }
        __shared__ float ss[4][2];
        if ((threadIdx.x & 63) == 0) { ss[wv][0] = lsum; ss[wv][1] = lsq; }
        __syncthreads();
        if (threadIdx.x == 0) {
            float a0 = 0.f, a1 = 0.f;
#pragma unroll
            for (int w = 0; w < 4; w++) { a0 += ss[w][0]; a1 += ss[w][1]; }
            atomicAdd(&cfg.stats[0], a0);
            atomicAdd(&cfg.stats[1], a1);
        }
    }
}

// ---------------- LN(A), LN(B), average; writes padded feat rows ----------
__global__ void lncomb_kernel(const float* __restrict__ ga, const float* __restrict__ gb,
                              const float* __restrict__ stats, float* __restrict__ h) {
    int i = blockIdx.x * blockDim.x + threadIdx.x;
    if (i >= NBT) return;
    const float M = (float)NBT;
    float ma = stats[0] / M; float va = stats[1] / M - ma * ma;
    float mb = stats[2] / M; float vb = stats[3] / M - mb * mb;
    float ra = rsqrtf(va + 1e-5f), rb = rsqrtf(vb + 1e-5f);
    int nb = i / DD, t = i - nb * DD;
    h[(size_t)nb * FS + t] = 0.5f * ((ga[i] - ma) * ra + (gb[i] - mb) * rb);
}

// ---------------- final combine ----------------
__global__ void outcomb_kernel(const float* __restrict__ reg, const float* __restrict__ ga,
                               const float* __restrict__ gb, float* __restrict__ out) {
    int i = blockIdx.x * blockDim.x + threadIdx.x;
    if (i >= NBT) return;
    int nb = i / DD;
    out[i] = (reg[nb] + ga[i] + gb[i]) * (1.0f / 3.0f);
}

extern "C" void kernel_launch(void* const* d_in, const int* in_sizes, int n_in,
                              void* d_out, int out_size, void* d_ws, size_t ws_size,
                              hipStream_t stream) {
    const float* x      = (const float*)d_in[0];
    const int* ps_src   = (const int*)d_in[1];
    const int* ps_dst   = (const int*)d_in[2];
    const int* rl_src   = (const int*)d_in[3];
    const int* rl_dst   = (const int*)d_in[4];
    const float* mu_p_fc = (const float*)d_in[5];
    const float* mu_p_al = (const float*)d_in[6];
    const float* mu_p_ar = (const float*)d_in[7];
    const float* sg_p_fc = (const float*)d_in[8];
    const float* sg_p_al = (const float*)d_in[9];
    const float* sg_p_ar = (const float*)d_in[10];
    const float* mu_r_fc = (const float*)d_in[11];
    const float* mu_r_al = (const float*)d_in[12];
    const float* mu_r_ar = (const float*)d_in[13];
    const float* sg_r_fc = (const float*)d_in[14];
    const float* sg_r_al = (const float*)d_in[15];
    const float* sg_r_ar = (const float*)d_in[16];
    const float* reg_mu_w = (const float*)d_in[17];
    const float* reg_mu_b = (const float*)d_in[18];
    const float* reg_sg_w = (const float*)d_in[19];
    const float* reg_sg_b = (const float*)d_in[20];

    float* out = (float*)d_out;

    // ---- workspace carve ----
    float* fw = (float*)d_ws;
    float* mu    = fw;              fw += NBF;   // padded stride-12 feats
    float* sigma = fw;              fw += NBF;
    float* hp    = fw;              fw += NBF;
    float* hrl   = fw;              fw += NBF;
    float* gA    = fw;              fw += NBT;   // stride-10 GAT outputs
    float* gB    = fw;              fw += NBT;
    float* gA2   = fw;              fw += NBT;
    float* gB2   = fw;              fw += NBT;
    float* regmu = fw;              fw += NB;
    float* regsg = fw;              fw += NB;
    float* vbuf  = fw;              fw += 8 * 80;
    int* iw = (int*)fw;
    int* ps_off = iw;               iw += NN + 1;
    int* rl_off = iw;               iw += NN + 1;
    int* ps_csr = iw;               iw += EE;
    int* rl_csr = iw;               iw += EE;
    int* ps_c8  = iw;               iw += NN * JJ;
    int* rl_c8  = iw;               iw += NN * JJ;
    // zero region starts here:
    int* deg_ps = iw;               iw += NN;
    int* cur_ps = iw;               iw += NN;
    int* deg_rl = iw;               iw += NN;
    int* cur_rl = iw;               iw += NN;
    float* stats = (float*)iw;      // 8 floats
    size_t zero_bytes = (size_t)(4 * NN) * sizeof(int) + 8 * sizeof(float);
    hipMemsetAsync(deg_ps, 0, zero_bytes, stream);

    const int TPB = 256;
    const int GRID_NB  = (NB + TPB - 1) / TPB;
    const int GRID_NBT = (NBT + TPB - 1) / TPB;
    const int GRID_E   = (EE + TPB - 1) / TPB;
    const int GRID_C8  = (NN * JJ + TPB - 1) / TPB;
    const int GRID_GAT = NB / 8;    // 40000: wave=2 nb, 4 waves/block

    extract_kernel<<<GRID_NB, TPB, 0, stream>>>(x, reg_mu_w, reg_mu_b, reg_sg_w, reg_sg_b,
                                                mu, sigma, regmu, regsg);

    // CSR (+padded csr8) for both graphs
    deg_kernel<<<GRID_E, TPB, 0, stream>>>(ps_dst, deg_ps);
    deg_kernel<<<GRID_E, TPB, 0, stream>>>(rl_dst, deg_rl);
    csr8init_kernel<<<GRID_C8, TPB, 0, stream>>>(ps_c8, rl_c8);
    scan_kernel<<<1, 1024, 0, stream>>>(deg_ps, ps_off);
    scan_kernel<<<1, 1024, 0, stream>>>(deg_rl, rl_off);
    fill_kernel<<<GRID_E, TPB, 0, stream>>>(ps_src, ps_dst, ps_off, cur_ps, ps_csr, ps_c8);
    fill_kernel<<<GRID_E, TPB, 0, stream>>>(rl_src, rl_dst, rl_off, cur_rl, rl_csr, rl_c8);

    // vl/vr precompute for all 8 GAT slots
    vpre_kernel<<<1, 320, 0, stream>>>(mu_p_fc, mu_p_al, mu_p_ar,
                                       sg_p_fc, sg_p_al, sg_p_ar,
                                       mu_r_fc, mu_r_al, mu_r_ar,
                                       sg_r_fc, sg_r_al, sg_r_ar, vbuf);

    // slots: 0 mu_p L0, 1 sg_p L0, 2 mu_r L0, 3 sg_r L0, 4 mu_p L1, 5 sg_p L1, 6 mu_r L1, 7 sg_r L1
    // ---- layer 0: 4 GATs in one dispatch ----
    {
        GatCfg4 c;
        c.c[0] = { mu,    mu_p_fc, vbuf + 0 * 80, ps_off, ps_csr, ps_c8, deg_ps, gA,  stats + 0 };
        c.c[1] = { sigma, sg_p_fc, vbuf + 1 * 80, ps_off, ps_csr, ps_c8, deg_ps, gB,  stats + 2 };
        c.c[2] = { mu,    mu_r_fc, vbuf + 2 * 80, rl_off, rl_csr, rl_c8, deg_rl, gA2, stats + 4 };
        c.c[3] = { sigma, sg_r_fc, vbuf + 3 * 80, rl_off, rl_csr, rl_c8, deg_rl, gB2, stats + 6 };
        dim3 grid(GRID_GAT, 4, 1);
        gat4_kernel<true><<<grid, TPB, 0, stream>>>(c);
    }
    lncomb_kernel<<<GRID_NBT, TPB, 0, stream>>>(gA, gB, stats + 0, hp);
    lncomb_kernel<<<GRID_NBT, TPB, 0, stream>>>(gA2, gB2, stats + 4, hrl);

    // ---- final layers: 4 GATs in one dispatch ----
    {
        GatCfg4 c;
        c.c[0] = { hp,  mu_p_fc + 400, vbuf + 4 * 80, ps_off, ps_csr, ps_c8, deg_ps, gA,  nullptr };
        c.c[1] = { hp,  sg_p_fc + 400, vbuf + 5 * 80, ps_off, ps_csr, ps_c8, deg_ps, gB,  nullptr };
        c.c[2] = { hrl, mu_r_fc + 400, vbuf + 6 * 80, rl_off, rl_csr, rl_c8, deg_rl, gA2, nullptr };
        c.c[3] = { hrl, sg_r_fc + 400, vbuf + 7 * 80, rl_off, rl_csr, rl_c8, deg_rl, gB2, nullptr };
        dim3 grid(GRID_GAT, 4, 1);
        gat4_kernel<false><<<grid, TPB, 0, stream>>>(c);
    }

    outcomb_kernel<<<GRID_NBT, TPB, 0, stream>>>(regmu, gA, gA2, out);
    outcomb_kernel<<<GRID_NBT, TPB, 0, stream>>>(regsg, gB, gB2, out + NBT);
}

// Round 9
// 1327.330 us; speedup vs baseline: 3.5300x; 3.5300x over previous
//
#include <hip/hip_runtime.h>

#define NN 10000
#define BB 32
#define EE 40000
#define HH 4
#define DD 10
#define TT 10
#define FS 12          // padded feat row stride (48 B, 16-B aligned)
#define NEG 0.2f

#define NB   (NN*BB)          // 320000
#define NBT  (NN*BB*TT)       // 3200000
#define NBF  (NN*BB*FS)       // 3840000 padded feat elems

// ---------------- extract mu/sigma + regression heads ----------------
__global__ void extract_kernel(const float* __restrict__ x,
                               const float* __restrict__ wmu, const float* __restrict__ bmu,
                               const float* __restrict__ wsg, const float* __restrict__ bsg,
                               float* __restrict__ mu, float* __restrict__ sg,
                               float* __restrict__ regmu, float* __restrict__ regsg) {
    int i = blockIdx.x * blockDim.x + threadIdx.x;   // over N*B
    if (i >= NB) return;
    int n = i / BB, b = i % BB;
    float smu = 0.f, ssg = 0.f;
    float muv[TT], sgv[TT];
#pragma unroll
    for (int t = 0; t < TT; t++) {
        size_t xi = (((size_t)t * NN + n) * BB + b) * 3;
        float m = x[xi], s = x[xi + 1];
        muv[t] = m; sgv[t] = s;
        smu += m * wmu[t];
        ssg += s * wsg[t];
    }
#pragma unroll
    for (int t = 0; t < TT; t++) {
        mu[(size_t)i * FS + t] = muv[t];
        sg[(size_t)i * FS + t] = sgv[t];
    }
    regmu[i] = smu + bmu[0];
    regsg[i] = ssg + bsg[0];
}

// ---------------- CSR build ----------------
__global__ void deg_kernel(const int* __restrict__ dst, int* __restrict__ deg) {
    int e = blockIdx.x * blockDim.x + threadIdx.x;
    if (e < EE) atomicAdd(&deg[dst[e]], 1);
}

__global__ void scan_kernel(const int* __restrict__ deg, int* __restrict__ off) {
    __shared__ int sm[1024];
    __shared__ int carry_s;
    if (threadIdx.x == 0) { carry_s = 0; off[0] = 0; }
    __syncthreads();
    for (int base = 0; base < NN; base += 1024) {
        int i = base + (int)threadIdx.x;
        int v = (i < NN) ? deg[i] : 0;
        sm[threadIdx.x] = v;
        __syncthreads();
        for (int s = 1; s < 1024; s <<= 1) {
            int t = (threadIdx.x >= (unsigned)s) ? sm[threadIdx.x - s] : 0;
            __syncthreads();
            sm[threadIdx.x] += t;
            __syncthreads();
        }
        if (i < NN) off[i + 1] = carry_s + sm[threadIdx.x];
        __syncthreads();
        if (threadIdx.x == 0) carry_s += sm[1023];
        __syncthreads();
    }
}

__global__ void fill_kernel(const int* __restrict__ src, const int* __restrict__ dst,
                            const int* __restrict__ off, int* __restrict__ cursor,
                            int* __restrict__ csr_src) {
    int e = blockIdx.x * blockDim.x + threadIdx.x;
    if (e < EE) {
        int d = dst[e];
        int p = atomicAdd(&cursor[d], 1);
        csr_src[off[d] + p] = src[e];
    }
}

// ---------------- precompute vl/vr for all 8 GATs ----------------
// vbuf layout: 8 slots of [vl(H*T=40) | vr(40)];
__global__ void vpre_kernel(const float* __restrict__ fc0, const float* __restrict__ al0, const float* __restrict__ ar0,
                            const float* __restrict__ fc1, const float* __restrict__ al1, const float* __restrict__ ar1,
                            const float* __restrict__ fc2, const float* __restrict__ al2, const float* __restrict__ ar2,
                            const float* __restrict__ fc3, const float* __restrict__ al3, const float* __restrict__ ar3,
                            float* __restrict__ vbuf) {
    int j = threadIdx.x;                 // 0..319
    if (j >= 320) return;
    int g = j / 40, r = j % 40;
    int h = r / 10, t = r % 10;
    int which = g & 3, layer = g >> 2;
    const float* fc; const float* al; const float* ar;
    if (which == 0)      { fc = fc0; al = al0; ar = ar0; }
    else if (which == 1) { fc = fc1; al = al1; ar = ar1; }
    else if (which == 2) { fc = fc2; al = al2; ar = ar2; }
    else                 { fc = fc3; al = al3; ar = ar3; }
    fc += layer * (HH * DD * TT);
    al += layer * (HH * DD);
    ar += layer * (HH * DD);
    float vl = 0.f, vr = 0.f;
#pragma unroll
    for (int d = 0; d < DD; d++) {
        float w = fc[(h * DD + d) * TT + t];
        vl += al[h * DD + d] * w;
        vr += ar[h * DD + d] * w;
    }
    vbuf[g * 80 + r] = vl;
    vbuf[g * 80 + 40 + r] = vr;
}

// ---------------- paired GAT: 2 GATs sharing one graph per pass ------------
// r9 design: lane = (b-slot 3b)(gat 1b)(head 2b); block = 1 node (32 b x 2
// gats x 4 heads = 256 thr). Edge list is blockIdx-uniform -> scalar loads.
// L0: gat0 gathers mu rows, gat1 sigma rows (independent loads, same index).
// Finals: fA==fB (hp/hrl) -> gat1's load is a broadcast dup (free).
// Per-lane live ~50 floats (r6's proven no-spill zone); acc fully private,
// only head-mean needs 2 shfl_xor. Halves edge-visit passes: 8 -> 4.
struct GatPairCfg {
    const float* fA; const float* fB;
    const float* WA; const float* WB;
    const float* vA; const float* vB;
    const int* off; const int* csr;
    float* gA; float* gB;
    float* statsA; float* statsB;
};
struct GatPairCfg2 { GatPairCfg c[2]; };

#define LOAD_ROW(dst, q)                                        \
    {                                                           \
        float4 _r0 = *(const float4*)(q);                       \
        float4 _r1 = *(const float4*)((q) + 4);                 \
        float2 _r2 = *(const float2*)((q) + 8);                 \
        dst[0]=_r0.x; dst[1]=_r0.y; dst[2]=_r0.z; dst[3]=_r0.w; \
        dst[4]=_r1.x; dst[5]=_r1.y; dst[6]=_r1.z; dst[7]=_r1.w; \
        dst[8]=_r2.x; dst[9]=_r2.y;                             \
    }

template <bool STATS>
__global__ void __launch_bounds__(256)
gatpair_kernel(GatPairCfg2 cfgs) {
    const GatPairCfg cfg = cfgs.c[blockIdx.y];
    __shared__ float sW[2][HH * DD * TT];   // 2 x 400
    __shared__ float sv[2][2 * HH * TT];    // 2 x 80: [vl(40) | vr(40)]
    for (int k = threadIdx.x; k < HH * DD * TT; k += blockDim.x) {
        sW[0][k] = cfg.WA[k]; sW[1][k] = cfg.WB[k];
    }
    if (threadIdx.x < 2 * HH * TT) {
        sv[0][threadIdx.x] = cfg.vA[threadIdx.x];
        sv[1][threadIdx.x] = cfg.vB[threadIdx.x];
    }
    __syncthreads();

    int lane = threadIdx.x & 63;
    int wv   = threadIdx.x >> 6;     // wave 0..3
    int h    = lane & 3;
    int gat  = (lane >> 2) & 1;
    int b8   = lane >> 3;            // 0..7
    int n    = blockIdx.x;
    int b    = wv * 8 + b8;          // 0..31
    int nb   = n * BB + b;

    const float* __restrict__ f = gat ? cfg.fB : cfg.fA;
    const float* fb_base = f + (size_t)b * FS;   // row = fb_base + s*BB*FS

    // attention vector for (gat, h) in registers
    float vl[TT];
#pragma unroll
    for (int t = 0; t < TT; t++) vl[t] = sv[gat][h * TT + t];

    int s0 = cfg.off[n], s1 = cfg.off[n + 1];    // blockIdx-uniform -> SGPR

    // er from self row
    float er = 0.f;
    {
        float fs[TT];
        LOAD_ROW(fs, f + (size_t)nb * FS);
#pragma unroll
        for (int t = 0; t < TT; t++) er += sv[gat][HH * TT + h * TT + t] * fs[t];
    }

    float acc[TT];
#pragma unroll
    for (int t = 0; t < TT; t++) acc[t] = 0.f;
    float den = 0.f;

    int k = s0;
    for (; k + 2 <= s1; k += 2) {
        int sA = cfg.csr[k], sB = cfg.csr[k + 1];    // uniform -> s_load
        float fa[TT], fb[TT];
        LOAD_ROW(fa, fb_base + (size_t)sA * (BB * FS));
        LOAD_ROW(fb, fb_base + (size_t)sB * (BB * FS));
        float ela = 0.f, elb = 0.f;
#pragma unroll
        for (int t = 0; t < TT; t++) {
            ela += vl[t] * fa[t];
            elb += vl[t] * fb[t];
        }
        float za = ela + er; za = (za >= 0.f) ? za : NEG * za;
        float zb = elb + er; zb = (zb >= 0.f) ? zb : NEG * zb;
        float wa = __expf(za), wb = __expf(zb);
        den += wa + wb;
#pragma unroll
        for (int t = 0; t < TT; t++) acc[t] += wa * fa[t] + wb * fb[t];
    }
    if (k < s1) {
        int sA = cfg.csr[k];
        float fa[TT];
        LOAD_ROW(fa, fb_base + (size_t)sA * (BB * FS));
        float ela = 0.f;
#pragma unroll
        for (int t = 0; t < TT; t++) ela += vl[t] * fa[t];
        float za = ela + er; za = (za >= 0.f) ? za : NEG * za;
        float wa = __expf(za);
        den += wa;
#pragma unroll
        for (int t = 0; t < TT; t++) acc[t] += wa * fa[t];
    }

    float rd = (s1 > s0) ? (1.0f / den) : 0.f;

    // W_(gat,h) on aggregated feat, leaky, 0.25; head-mean via shfl_xor(1,2)
    const float* sWg = sW[gat];
    float outv[DD];
#pragma unroll
    for (int d = 0; d < DD; d++) {
        float va = 0.f;
#pragma unroll
        for (int t = 0; t < TT; t++) va += sWg[(h * DD + d) * TT + t] * acc[t];
        va *= rd;
        va = (va >= 0.f) ? va : NEG * va;
        outv[d] = va * 0.25f;
    }
#pragma unroll
    for (int d = 0; d < DD; d++) {
        outv[d] += __shfl_xor(outv[d], 1, 64);
        outv[d] += __shfl_xor(outv[d], 2, 64);
    }

    float lsA = 0.f, lqA = 0.f, lsB = 0.f, lqB = 0.f;
    if (h == 0) {
        float* gp = (gat ? cfg.gB : cfg.gA) + (size_t)nb * DD;
        float s = 0.f, q = 0.f;
#pragma unroll
        for (int d = 0; d < DD; d++) {
            float o = outv[d];
            gp[d] = o;
            s += o; q += o * o;
        }
        if (STATS) {
            if (gat == 0) { lsA = s; lqA = q; } else { lsB = s; lqB = q; }
        }
    }
    if (STATS) {
#pragma unroll
        for (int o = 32; o > 0; o >>= 1) {
            lsA += __shfl_down(lsA, o, 64);
            lqA += __shfl_down(lqA, o, 64);
            lsB += __shfl_down(lsB, o, 64);
            lqB += __shfl_down(lqB, o, 64);
        }
        __shared__ float ss[4][4];
        if (lane == 0) { ss[wv][0] = lsA; ss[wv][1] = lqA; ss[wv][2] = lsB; ss[wv][3] = lqB; }
        __syncthreads();
        if (threadIdx.x == 0) {
            float a0 = 0.f, a1 = 0.f, a2 = 0.f, a3 = 0.f;
#pragma unroll
            for (int w = 0; w < 4; w++) { a0 += ss[w][0]; a1 += ss[w][1]; a2 += ss[w][2]; a3 += ss[w][3]; }
            atomicAdd(&cfg.statsA[0], a0);
            atomicAdd(&cfg.statsA[1], a1);
            atomicAdd(&cfg.statsB[0], a2);
            atomicAdd(&cfg.statsB[1], a3);
        }
    }
}

// ---------------- LN(A), LN(B), average; writes padded feat rows ----------
__global__ void lncomb_kernel(const float* __restrict__ ga, const float* __restrict__ gb,
                              const float* __restrict__ stats, float* __restrict__ h) {
    int i = blockIdx.x * blockDim.x + threadIdx.x;
    if (i >= NBT) return;
    const float M = (float)NBT;
    float ma = stats[0] / M; float va = stats[1] / M - ma * ma;
    float mb = stats[2] / M; float vb = stats[3] / M - mb * mb;
    float ra = rsqrtf(va + 1e-5f), rb = rsqrtf(vb + 1e-5f);
    int nb = i / DD, t = i - nb * DD;
    h[(size_t)nb * FS + t] = 0.5f * ((ga[i] - ma) * ra + (gb[i] - mb) * rb);
}

// ---------------- final combine ----------------
__global__ void outcomb_kernel(const float* __restrict__ reg, const float* __restrict__ ga,
                               const float* __restrict__ gb, float* __restrict__ out) {
    int i = blockIdx.x * blockDim.x + threadIdx.x;
    if (i >= NBT) return;
    int nb = i / DD;
    out[i] = (reg[nb] + ga[i] + gb[i]) * (1.0f / 3.0f);
}

extern "C" void kernel_launch(void* const* d_in, const int* in_sizes, int n_in,
                              void* d_out, int out_size, void* d_ws, size_t ws_size,
                              hipStream_t stream) {
    const float* x      = (const float*)d_in[0];
    const int* ps_src   = (const int*)d_in[1];
    const int* ps_dst   = (const int*)d_in[2];
    const int* rl_src   = (const int*)d_in[3];
    const int* rl_dst   = (const int*)d_in[4];
    const float* mu_p_fc = (const float*)d_in[5];
    const float* mu_p_al = (const float*)d_in[6];
    const float* mu_p_ar = (const float*)d_in[7];
    const float* sg_p_fc = (const float*)d_in[8];
    const float* sg_p_al = (const float*)d_in[9];
    const float* sg_p_ar = (const float*)d_in[10];
    const float* mu_r_fc = (const float*)d_in[11];
    const float* mu_r_al = (const float*)d_in[12];
    const float* mu_r_ar = (const float*)d_in[13];
    const float* sg_r_fc = (const float*)d_in[14];
    const float* sg_r_al = (const float*)d_in[15];
    const float* sg_r_ar = (const float*)d_in[16];
    const float* reg_mu_w = (const float*)d_in[17];
    const float* reg_mu_b = (const float*)d_in[18];
    const float* reg_sg_w = (const float*)d_in[19];
    const float* reg_sg_b = (const float*)d_in[20];

    float* out = (float*)d_out;

    // ---- workspace carve ----
    float* fw = (float*)d_ws;
    float* mu    = fw;              fw += NBF;   // padded stride-12 feats
    float* sigma = fw;              fw += NBF;
    float* hp    = fw;              fw += NBF;
    float* hrl   = fw;              fw += NBF;
    float* gA    = fw;              fw += NBT;   // stride-10 GAT outputs
    float* gB    = fw;              fw += NBT;
    float* gA2   = fw;              fw += NBT;
    float* gB2   = fw;              fw += NBT;
    float* regmu = fw;              fw += NB;
    float* regsg = fw;              fw += NB;
    float* vbuf  = fw;              fw += 8 * 80;
    int* iw = (int*)fw;
    int* ps_off = iw;               iw += NN + 1;
    int* rl_off = iw;               iw += NN + 1;
    int* ps_csr = iw;               iw += EE;
    int* rl_csr = iw;               iw += EE;
    // zero region starts here:
    int* deg_ps = iw;               iw += NN;
    int* cur_ps = iw;               iw += NN;
    int* deg_rl = iw;               iw += NN;
    int* cur_rl = iw;               iw += NN;
    float* stats = (float*)iw;      // 8 floats
    size_t zero_bytes = (size_t)(4 * NN) * sizeof(int) + 8 * sizeof(float);
    hipMemsetAsync(deg_ps, 0, zero_bytes, stream);

    const int TPB = 256;
    const int GRID_NB  = (NB + TPB - 1) / TPB;
    const int GRID_NBT = (NBT + TPB - 1) / TPB;
    const int GRID_E   = (EE + TPB - 1) / TPB;

    extract_kernel<<<GRID_NB, TPB, 0, stream>>>(x, reg_mu_w, reg_mu_b, reg_sg_w, reg_sg_b,
                                                mu, sigma, regmu, regsg);

    // CSR for both graphs
    deg_kernel<<<GRID_E, TPB, 0, stream>>>(ps_dst, deg_ps);
    deg_kernel<<<GRID_E, TPB, 0, stream>>>(rl_dst, deg_rl);
    scan_kernel<<<1, 1024, 0, stream>>>(deg_ps, ps_off);
    scan_kernel<<<1, 1024, 0, stream>>>(deg_rl, rl_off);
    fill_kernel<<<GRID_E, TPB, 0, stream>>>(ps_src, ps_dst, ps_off, cur_ps, ps_csr);
    fill_kernel<<<GRID_E, TPB, 0, stream>>>(rl_src, rl_dst, rl_off, cur_rl, rl_csr);

    // vl/vr precompute for all 8 GAT slots
    vpre_kernel<<<1, 320, 0, stream>>>(mu_p_fc, mu_p_al, mu_p_ar,
                                       sg_p_fc, sg_p_al, sg_p_ar,
                                       mu_r_fc, mu_r_al, mu_r_ar,
                                       sg_r_fc, sg_r_al, sg_r_ar, vbuf);

    // slots: 0 mu_p L0, 1 sg_p L0, 2 mu_r L0, 3 sg_r L0, 4 mu_p L1, 5 sg_p L1, 6 mu_r L1, 7 sg_r L1
    // ---- layer 0: (mu,sg) pairs on both graphs, one dispatch ----
    {
        GatPairCfg2 c;
        c.c[0] = { mu, sigma, mu_p_fc, sg_p_fc, vbuf + 0 * 80, vbuf + 1 * 80,
                   ps_off, ps_csr, gA,  gB,  stats + 0, stats + 2 };
        c.c[1] = { mu, sigma, mu_r_fc, sg_r_fc, vbuf + 2 * 80, vbuf + 3 * 80,
                   rl_off, rl_csr, gA2, gB2, stats + 4, stats + 6 };
        dim3 grid(NN, 2, 1);
        gatpair_kernel<true><<<grid, TPB, 0, stream>>>(c);
    }
    lncomb_kernel<<<GRID_NBT, TPB, 0, stream>>>(gA, gB, stats + 0, hp);
    lncomb_kernel<<<GRID_NBT, TPB, 0, stream>>>(gA2, gB2, stats + 4, hrl);

    // ---- final layers: (mu,sg) pairs sharing feat, one dispatch ----
    {
        GatPairCfg2 c;
        c.c[0] = { hp,  hp,  mu_p_fc + 400, sg_p_fc + 400, vbuf + 4 * 80, vbuf + 5 * 80,
                   ps_off, ps_csr, gA,  gB,  nullptr, nullptr };
        c.c[1] = { hrl, hrl, mu_r_fc + 400, sg_r_fc + 400, vbuf + 6 * 80, vbuf + 7 * 80,
                   rl_off, rl_csr, gA2, gB2, nullptr, nullptr };
        dim3 grid(NN, 2, 1);
        gatpair_kernel<false><<<grid, TPB, 0, stream>>>(c);
    }

    outcomb_kernel<<<GRID_NBT, TPB, 0, stream>>>(regmu, gA, gA2, out);
    outcomb_kernel<<<GRID_NBT, TPB, 0, stream>>>(regsg, gB, gB2, out + NBT);
}

// Round 10
// 868.750 us; speedup vs baseline: 5.3934x; 1.5279x over previous
//
#include <hip/hip_runtime.h>

#define NN 10000
#define BB 32
#define EE 40000
#define HH 4
#define DD 10
#define TT 10
#define FS 12          // padded feat row stride (48 B, 16-B aligned)
#define NEG 0.2f

#define NB   (NN*BB)          // 320000
#define NBH_T (NB*HH)         // 1280000 threads for gat kernels
#define NBT  (NN*BB*TT)       // 3200000
#define NBF  (NN*BB*FS)       // 3840000 padded feat elems

// ---------------- extract mu/sigma + regression heads ----------------
__global__ void extract_kernel(const float* __restrict__ x,
                               const float* __restrict__ wmu, const float* __restrict__ bmu,
                               const float* __restrict__ wsg, const float* __restrict__ bsg,
                               float* __restrict__ mu, float* __restrict__ sg,
                               float* __restrict__ regmu, float* __restrict__ regsg) {
    int i = blockIdx.x * blockDim.x + threadIdx.x;   // over N*B
    if (i >= NB) return;
    int n = i / BB, b = i % BB;
    float smu = 0.f, ssg = 0.f;
    float muv[TT], sgv[TT];
#pragma unroll
    for (int t = 0; t < TT; t++) {
        size_t xi = (((size_t)t * NN + n) * BB + b) * 3;
        float m = x[xi], s = x[xi + 1];
        muv[t] = m; sgv[t] = s;
        smu += m * wmu[t];
        ssg += s * wsg[t];
    }
#pragma unroll
    for (int t = 0; t < TT; t++) {
        mu[(size_t)i * FS + t] = muv[t];
        sg[(size_t)i * FS + t] = sgv[t];
    }
    regmu[i] = smu + bmu[0];
    regsg[i] = ssg + bsg[0];
}

// ---------------- CSR build ----------------
__global__ void deg_kernel(const int* __restrict__ dst, int* __restrict__ deg) {
    int e = blockIdx.x * blockDim.x + threadIdx.x;
    if (e < EE) atomicAdd(&deg[dst[e]], 1);
}

__global__ void scan_kernel(const int* __restrict__ deg, int* __restrict__ off) {
    __shared__ int sm[1024];
    __shared__ int carry_s;
    if (threadIdx.x == 0) { carry_s = 0; off[0] = 0; }
    __syncthreads();
    for (int base = 0; base < NN; base += 1024) {
        int i = base + (int)threadIdx.x;
        int v = (i < NN) ? deg[i] : 0;
        sm[threadIdx.x] = v;
        __syncthreads();
        for (int s = 1; s < 1024; s <<= 1) {
            int t = (threadIdx.x >= (unsigned)s) ? sm[threadIdx.x - s] : 0;
            __syncthreads();
            sm[threadIdx.x] += t;
            __syncthreads();
        }
        if (i < NN) off[i + 1] = carry_s + sm[threadIdx.x];
        __syncthreads();
        if (threadIdx.x == 0) carry_s += sm[1023];
        __syncthreads();
    }
}

__global__ void fill_kernel(const int* __restrict__ src, const int* __restrict__ dst,
                            const int* __restrict__ off, int* __restrict__ cursor,
                            int* __restrict__ csr_src) {
    int e = blockIdx.x * blockDim.x + threadIdx.x;
    if (e < EE) {
        int d = dst[e];
        int p = atomicAdd(&cursor[d], 1);
        csr_src[off[d] + p] = src[e];
    }
}

// ---------------- precompute vl/vr for all 8 GATs ----------------
// vbuf layout: 8 slots of [vl(H*T=40) | vr(40)];
__global__ void vpre_kernel(const float* __restrict__ fc0, const float* __restrict__ al0, const float* __restrict__ ar0,
                            const float* __restrict__ fc1, const float* __restrict__ al1, const float* __restrict__ ar1,
                            const float* __restrict__ fc2, const float* __restrict__ al2, const float* __restrict__ ar2,
                            const float* __restrict__ fc3, const float* __restrict__ al3, const float* __restrict__ ar3,
                            float* __restrict__ vbuf) {
    int j = threadIdx.x;                 // 0..319
    if (j >= 320) return;
    int g = j / 40, r = j % 40;
    int h = r / 10, t = r % 10;
    int which = g & 3, layer = g >> 2;
    const float* fc; const float* al; const float* ar;
    if (which == 0)      { fc = fc0; al = al0; ar = ar0; }
    else if (which == 1) { fc = fc1; al = al1; ar = ar1; }
    else if (which == 2) { fc = fc2; al = al2; ar = ar2; }
    else                 { fc = fc3; al = al3; ar = ar3; }
    fc += layer * (HH * DD * TT);
    al += layer * (HH * DD);
    ar += layer * (HH * DD);
    float vl = 0.f, vr = 0.f;
#pragma unroll
    for (int d = 0; d < DD; d++) {
        float w = fc[(h * DD + d) * TT + t];
        vl += al[h * DD + d] * w;
        vr += ar[h * DD + d] * w;
    }
    vbuf[g * 80 + r] = vl;
    vbuf[g * 80 + 40 + r] = vr;
}

// ---------------- dual-GAT pass, thread per (node, batch, head) -------------
// r10: halve edge-visit passes (8 -> 4) by fusing GAT pairs that share a
// graph into one gather loop with TWO accumulators. Register discipline
// (the r2/r3 lesson: ~170 live spills; r4/r5: ~85 spills; r6: ~50 clean):
// vl/vr/W stay in LDS (4-addr broadcast reads, conflict-free), keeping live
// state ~55 floats: accA[10]+accB[10] + row regs + scalars.
// SAMEF (finals): one row stream serves both GATs, 2-edge unroll.
// !SAMEF (L0): two row streams (mu+sigma, same index), 1-edge loop.
// Wave layout: i=(nb<<2)|h -> 16 consecutive nb x 4 heads, one node/wave.
struct GatDualCfg {
    const float* fA; const float* fB;
    const float* WA; const float* WB;
    const float* vA; const float* vB;
    const int* off; const int* csr;
    float* gA; float* gB;
    float* statsA; float* statsB;
};
struct GatDualCfg2 { GatDualCfg c[2]; };

#define LOAD_ROW(dst, q)                                        \
    {                                                           \
        float4 _r0 = *(const float4*)(q);                       \
        float4 _r1 = *(const float4*)((q) + 4);                 \
        float2 _r2 = *(const float2*)((q) + 8);                 \
        dst[0]=_r0.x; dst[1]=_r0.y; dst[2]=_r0.z; dst[3]=_r0.w; \
        dst[4]=_r1.x; dst[5]=_r1.y; dst[6]=_r1.z; dst[7]=_r1.w; \
        dst[8]=_r2.x; dst[9]=_r2.y;                             \
    }

template <bool STATS, bool SAMEF>
__global__ void __launch_bounds__(256)
gatdual_kernel(GatDualCfg2 cfgs) {
    const GatDualCfg cfg = cfgs.c[blockIdx.y];
    __shared__ float sWA[HH * DD * TT], sWB[HH * DD * TT];   // 400 each
    __shared__ float svA[2 * HH * TT],  svB[2 * HH * TT];    // 80 each
    for (int k = threadIdx.x; k < HH * DD * TT; k += blockDim.x) {
        sWA[k] = cfg.WA[k]; sWB[k] = cfg.WB[k];
    }
    if (threadIdx.x < 2 * HH * TT) {
        svA[threadIdx.x] = cfg.vA[threadIdx.x];
        svB[threadIdx.x] = cfg.vB[threadIdx.x];
    }
    __syncthreads();

    const float* __restrict__ fA = cfg.fA;
    const float* __restrict__ fB = cfg.fB;
    const int* __restrict__ csr = cfg.csr;

    int i = blockIdx.x * blockDim.x + threadIdx.x;   // over NB*HH
    float lsA = 0.f, lqA = 0.f, lsB = 0.f, lqB = 0.f;
    if (i < NBH_T) {
        int h  = i & 3;
        int nb = i >> 2;          // n*32 + b
        int b  = nb & 31;
        int n  = nb >> 5;
        int s0 = cfg.off[n], s1 = cfg.off[n + 1];

        // er from self rows (rows dead after this)
        float erA = 0.f, erB = 0.f;
        {
            float fsA[TT];
            LOAD_ROW(fsA, fA + (size_t)nb * FS);
            if (SAMEF) {
#pragma unroll
                for (int t = 0; t < TT; t++) {
                    erA += svA[HH * TT + h * TT + t] * fsA[t];
                    erB += svB[HH * TT + h * TT + t] * fsA[t];
                }
            } else {
                float fsB[TT];
                LOAD_ROW(fsB, fB + (size_t)nb * FS);
#pragma unroll
                for (int t = 0; t < TT; t++) {
                    erA += svA[HH * TT + h * TT + t] * fsA[t];
                    erB += svB[HH * TT + h * TT + t] * fsB[t];
                }
            }
        }

        float accA[TT], accB[TT];
#pragma unroll
        for (int t = 0; t < TT; t++) { accA[t] = 0.f; accB[t] = 0.f; }
        float denA = 0.f, denB = 0.f;

        if (SAMEF) {
            // one row stream, 2-edge unroll, two accumulators
            int k = s0;
            for (; k + 2 <= s1; k += 2) {
                int sA = csr[k], sB = csr[k + 1];
                const float* qa = fA + (size_t)(sA * BB + b) * FS;
                const float* qb = fA + (size_t)(sB * BB + b) * FS;
                float fa[TT], fb[TT];
                LOAD_ROW(fa, qa);
                LOAD_ROW(fb, qb);
                float eAa = 0.f, eAb = 0.f, eBa = 0.f, eBb = 0.f;
#pragma unroll
                for (int t = 0; t < TT; t++) {
                    float va = svA[h * TT + t], vb = svB[h * TT + t];
                    eAa += va * fa[t]; eAb += va * fb[t];
                    eBa += vb * fa[t]; eBb += vb * fb[t];
                }
                float zAa = eAa + erA; zAa = (zAa >= 0.f) ? zAa : NEG * zAa;
                float zAb = eAb + erA; zAb = (zAb >= 0.f) ? zAb : NEG * zAb;
                float zBa = eBa + erB; zBa = (zBa >= 0.f) ? zBa : NEG * zBa;
                float zBb = eBb + erB; zBb = (zBb >= 0.f) ? zBb : NEG * zBb;
                float wAa = __expf(zAa), wAb = __expf(zAb);
                float wBa = __expf(zBa), wBb = __expf(zBb);
                denA += wAa + wAb; denB += wBa + wBb;
#pragma unroll
                for (int t = 0; t < TT; t++) {
                    accA[t] += wAa * fa[t] + wAb * fb[t];
                    accB[t] += wBa * fa[t] + wBb * fb[t];
                }
            }
            if (k < s1) {
                int sA = csr[k];
                const float* qa = fA + (size_t)(sA * BB + b) * FS;
                float fa[TT];
                LOAD_ROW(fa, qa);
                float eAa = 0.f, eBa = 0.f;
#pragma unroll
                for (int t = 0; t < TT; t++) {
                    eAa += svA[h * TT + t] * fa[t];
                    eBa += svB[h * TT + t] * fa[t];
                }
                float zAa = eAa + erA; zAa = (zAa >= 0.f) ? zAa : NEG * zAa;
                float zBa = eBa + erB; zBa = (zBa >= 0.f) ? zBa : NEG * zBa;
                float wAa = __expf(zAa), wBa = __expf(zBa);
                denA += wAa; denB += wBa;
#pragma unroll
                for (int t = 0; t < TT; t++) {
                    accA[t] += wAa * fa[t];
                    accB[t] += wBa * fa[t];
                }
            }
        } else {
            // two row streams (same index), 1-edge loop
            for (int k = s0; k < s1; k++) {
                int sA = csr[k];
                size_t ro = (size_t)(sA * BB + b) * FS;
                float fa[TT], fb[TT];
                LOAD_ROW(fa, fA + ro);
                LOAD_ROW(fb, fB + ro);
                float eA = 0.f, eB = 0.f;
#pragma unroll
                for (int t = 0; t < TT; t++) {
                    eA += svA[h * TT + t] * fa[t];
                    eB += svB[h * TT + t] * fb[t];
                }
                float zA = eA + erA; zA = (zA >= 0.f) ? zA : NEG * zA;
                float zB = eB + erB; zB = (zB >= 0.f) ? zB : NEG * zB;
                float wA = __expf(zA), wB = __expf(zB);
                denA += wA; denB += wB;
#pragma unroll
                for (int t = 0; t < TT; t++) {
                    accA[t] += wA * fa[t];
                    accB[t] += wB * fb[t];
                }
            }
        }

        bool nz = (s1 > s0);
        float rdA = nz ? (1.0f / denA) : 0.f;
        float rdB = nz ? (1.0f / denB) : 0.f;

        // W applies from LDS, leaky, 0.25, head-mean via shfl_xor
        float outA[DD], outB[DD];
#pragma unroll
        for (int d = 0; d < DD; d++) {
            float va = 0.f, vb = 0.f;
#pragma unroll
            for (int t = 0; t < TT; t++) {
                va += sWA[(h * DD + d) * TT + t] * accA[t];
                vb += sWB[(h * DD + d) * TT + t] * accB[t];
            }
            va *= rdA; vb *= rdB;
            va = (va >= 0.f) ? va : NEG * va;
            vb = (vb >= 0.f) ? vb : NEG * vb;
            outA[d] = va * 0.25f;
            outB[d] = vb * 0.25f;
        }
#pragma unroll
        for (int d = 0; d < DD; d++) {
            outA[d] += __shfl_xor(outA[d], 1, 64);
            outA[d] += __shfl_xor(outA[d], 2, 64);
            outB[d] += __shfl_xor(outB[d], 1, 64);
            outB[d] += __shfl_xor(outB[d], 2, 64);
        }
        if (h == 0) {
            float* gpa = cfg.gA + (size_t)nb * DD;
            float* gpb = cfg.gB + (size_t)nb * DD;
#pragma unroll
            for (int d = 0; d < DD; d++) {
                float oa = outA[d], ob = outB[d];
                gpa[d] = oa; gpb[d] = ob;
                if (STATS) { lsA += oa; lqA += oa * oa; lsB += ob; lqB += ob * ob; }
            }
        }
    }
    if (STATS) {
#pragma unroll
        for (int o = 32; o > 0; o >>= 1) {
            lsA += __shfl_down(lsA, o, 64);
            lqA += __shfl_down(lqA, o, 64);
            lsB += __shfl_down(lsB, o, 64);
            lqB += __shfl_down(lqB, o, 64);
        }
        __shared__ float ss[4][4];
        int wid = threadIdx.x >> 6, lid = threadIdx.x & 63;
        if (lid == 0) { ss[wid][0] = lsA; ss[wid][1] = lqA; ss[wid][2] = lsB; ss[wid][3] = lqB; }
        __syncthreads();
        if (threadIdx.x == 0) {
            float a0 = 0.f, a1 = 0.f, a2 = 0.f, a3 = 0.f;
#pragma unroll
            for (int w = 0; w < 4; w++) { a0 += ss[w][0]; a1 += ss[w][1]; a2 += ss[w][2]; a3 += ss[w][3]; }
            atomicAdd(&cfg.statsA[0], a0);
            atomicAdd(&cfg.statsA[1], a1);
            atomicAdd(&cfg.statsB[0], a2);
            atomicAdd(&cfg.statsB[1], a3);
        }
    }
}

// ---------------- LN(A), LN(B), average; writes padded feat rows ----------
__global__ void lncomb_kernel(const float* __restrict__ ga, const float* __restrict__ gb,
                              const float* __restrict__ stats, float* __restrict__ h) {
    int i = blockIdx.x * blockDim.x + threadIdx.x;
    if (i >= NBT) return;
    const float M = (float)NBT;
    float ma = stats[0] / M; float va = stats[1] / M - ma * ma;
    float mb = stats[2] / M; float vb = stats[3] / M - mb * mb;
    float ra = rsqrtf(va + 1e-5f), rb = rsqrtf(vb + 1e-5f);
    int nb = i / DD, t = i - nb * DD;
    h[(size_t)nb * FS + t] = 0.5f * ((ga[i] - ma) * ra + (gb[i] - mb) * rb);
}

// ---------------- final combine ----------------
__global__ void outcomb_kernel(const float* __restrict__ reg, const float* __restrict__ ga,
                               const float* __restrict__ gb, float* __restrict__ out) {
    int i = blockIdx.x * blockDim.x + threadIdx.x;
    if (i >= NBT) return;
    int nb = i / DD;
    out[i] = (reg[nb] + ga[i] + gb[i]) * (1.0f / 3.0f);
}

extern "C" void kernel_launch(void* const* d_in, const int* in_sizes, int n_in,
                              void* d_out, int out_size, void* d_ws, size_t ws_size,
                              hipStream_t stream) {
    const float* x      = (const float*)d_in[0];
    const int* ps_src   = (const int*)d_in[1];
    const int* ps_dst   = (const int*)d_in[2];
    const int* rl_src   = (const int*)d_in[3];
    const int* rl_dst   = (const int*)d_in[4];
    const float* mu_p_fc = (const float*)d_in[5];
    const float* mu_p_al = (const float*)d_in[6];
    const float* mu_p_ar = (const float*)d_in[7];
    const float* sg_p_fc = (const float*)d_in[8];
    const float* sg_p_al = (const float*)d_in[9];
    const float* sg_p_ar = (const float*)d_in[10];
    const float* mu_r_fc = (const float*)d_in[11];
    const float* mu_r_al = (const float*)d_in[12];
    const float* mu_r_ar = (const float*)d_in[13];
    const float* sg_r_fc = (const float*)d_in[14];
    const float* sg_r_al = (const float*)d_in[15];
    const float* sg_r_ar = (const float*)d_in[16];
    const float* reg_mu_w = (const float*)d_in[17];
    const float* reg_mu_b = (const float*)d_in[18];
    const float* reg_sg_w = (const float*)d_in[19];
    const float* reg_sg_b = (const float*)d_in[20];

    float* out = (float*)d_out;

    // ---- workspace carve ----
    float* fw = (float*)d_ws;
    float* mu    = fw;              fw += NBF;   // padded stride-12 feats
    float* sigma = fw;              fw += NBF;
    float* hp    = fw;              fw += NBF;
    float* hrl   = fw;              fw += NBF;
    float* gA    = fw;              fw += NBT;   // stride-10 GAT outputs
    float* gB    = fw;              fw += NBT;
    float* gA2   = fw;              fw += NBT;
    float* gB2   = fw;              fw += NBT;
    float* regmu = fw;              fw += NB;
    float* regsg = fw;              fw += NB;
    float* vbuf  = fw;              fw += 8 * 80;
    int* iw = (int*)fw;
    int* ps_off = iw;               iw += NN + 1;
    int* rl_off = iw;               iw += NN + 1;
    int* ps_csr = iw;               iw += EE;
    int* rl_csr = iw;               iw += EE;
    // zero region starts here:
    int* deg_ps = iw;               iw += NN;
    int* cur_ps = iw;               iw += NN;
    int* deg_rl = iw;               iw += NN;
    int* cur_rl = iw;               iw += NN;
    float* stats = (float*)iw;      // 8 floats
    size_t zero_bytes = (size_t)(4 * NN) * sizeof(int) + 8 * sizeof(float);
    hipMemsetAsync(deg_ps, 0, zero_bytes, stream);

    const int TPB = 256;
    const int GRID_NB  = (NB + TPB - 1) / TPB;
    const int GRID_NBH = (NBH_T + TPB - 1) / TPB;   // 5000
    const int GRID_NBT = (NBT + TPB - 1) / TPB;
    const int GRID_E   = (EE + TPB - 1) / TPB;

    extract_kernel<<<GRID_NB, TPB, 0, stream>>>(x, reg_mu_w, reg_mu_b, reg_sg_w, reg_sg_b,
                                                mu, sigma, regmu, regsg);

    // CSR for both graphs
    deg_kernel<<<GRID_E, TPB, 0, stream>>>(ps_dst, deg_ps);
    deg_kernel<<<GRID_E, TPB, 0, stream>>>(rl_dst, deg_rl);
    scan_kernel<<<1, 1024, 0, stream>>>(deg_ps, ps_off);
    scan_kernel<<<1, 1024, 0, stream>>>(deg_rl, rl_off);
    fill_kernel<<<GRID_E, TPB, 0, stream>>>(ps_src, ps_dst, ps_off, cur_ps, ps_csr);
    fill_kernel<<<GRID_E, TPB, 0, stream>>>(rl_src, rl_dst, rl_off, cur_rl, rl_csr);

    // vl/vr precompute for all 8 GAT slots
    vpre_kernel<<<1, 320, 0, stream>>>(mu_p_fc, mu_p_al, mu_p_ar,
                                       sg_p_fc, sg_p_al, sg_p_ar,
                                       mu_r_fc, mu_r_al, mu_r_ar,
                                       sg_r_fc, sg_r_al, sg_r_ar, vbuf);

    // slots: 0 mu_p L0, 1 sg_p L0, 2 mu_r L0, 3 sg_r L0, 4 mu_p L1, 5 sg_p L1, 6 mu_r L1, 7 sg_r L1
    // ---- layer 0: (mu,sg) pairs on ps and rl, one dispatch (grid.y=2) ----
    {
        GatDualCfg2 c;
        c.c[0] = { mu, sigma, mu_p_fc, sg_p_fc, vbuf + 0 * 80, vbuf + 1 * 80,
                   ps_off, ps_csr, gA,  gB,  stats + 0, stats + 2 };
        c.c[1] = { mu, sigma, mu_r_fc, sg_r_fc, vbuf + 2 * 80, vbuf + 3 * 80,
                   rl_off, rl_csr, gA2, gB2, stats + 4, stats + 6 };
        dim3 grid(GRID_NBH, 2, 1);
        gatdual_kernel<true, false><<<grid, TPB, 0, stream>>>(c);
    }
    lncomb_kernel<<<GRID_NBT, TPB, 0, stream>>>(gA, gB, stats + 0, hp);
    lncomb_kernel<<<GRID_NBT, TPB, 0, stream>>>(gA2, gB2, stats + 4, hrl);

    // ---- final layers: (mu,sg) pairs sharing feat, one dispatch ----
    {
        GatDualCfg2 c;
        c.c[0] = { hp,  hp,  mu_p_fc + 400, sg_p_fc + 400, vbuf + 4 * 80, vbuf + 5 * 80,
                   ps_off, ps_csr, gA,  gB,  nullptr, nullptr };
        c.c[1] = { hrl, hrl, mu_r_fc + 400, sg_r_fc + 400, vbuf + 6 * 80, vbuf + 7 * 80,
                   rl_off, rl_csr, gA2, gB2, nullptr, nullptr };
        dim3 grid(GRID_NBH, 2, 1);
        gatdual_kernel<false, true><<<grid, TPB, 0, stream>>>(c);
    }

    outcomb_kernel<<<GRID_NBT, TPB, 0, stream>>>(regmu, gA, gA2, out);
    outcomb_kernel<<<GRID_NBT, TPB, 0, stream>>>(regsg, gB, gB2, out + NBT);
}

// Round 11
// 850.757 us; speedup vs baseline: 5.5074x; 1.0211x over previous
//
#include <hip/hip_runtime.h>

#define NN 10000
#define BB 32
#define EE 40000
#define HH 4
#define DD 10
#define TT 10
#define FS 12          // padded feat row stride (48 B, 16-B aligned)
#define JJ 8           // padded edge slots per node
#define NEG 0.2f

#define NB   (NN*BB)          // 320000
#define NBH_T (NB*HH)         // 1280000 threads for gat kernels
#define NBT  (NN*BB*TT)       // 3200000
#define NBF  (NN*BB*FS)       // 3840000 padded feat elems

// ---------------- extract mu/sigma + regression heads ----------------
__global__ void extract_kernel(const float* __restrict__ x,
                               const float* __restrict__ wmu, const float* __restrict__ bmu,
                               const float* __restrict__ wsg, const float* __restrict__ bsg,
                               float* __restrict__ mu, float* __restrict__ sg,
                               float* __restrict__ regmu, float* __restrict__ regsg) {
    int i = blockIdx.x * blockDim.x + threadIdx.x;   // over N*B
    if (i >= NB) return;
    int n = i / BB, b = i % BB;
    float smu = 0.f, ssg = 0.f;
    float muv[TT], sgv[TT];
#pragma unroll
    for (int t = 0; t < TT; t++) {
        size_t xi = (((size_t)t * NN + n) * BB + b) * 3;
        float m = x[xi], s = x[xi + 1];
        muv[t] = m; sgv[t] = s;
        smu += m * wmu[t];
        ssg += s * wsg[t];
    }
#pragma unroll
    for (int t = 0; t < TT; t++) {
        mu[(size_t)i * FS + t] = muv[t];
        sg[(size_t)i * FS + t] = sgv[t];
    }
    regmu[i] = smu + bmu[0];
    regsg[i] = ssg + bsg[0];
}

// ---------------- CSR build ----------------
__global__ void deg_kernel(const int* __restrict__ dst, int* __restrict__ deg) {
    int e = blockIdx.x * blockDim.x + threadIdx.x;
    if (e < EE) atomicAdd(&deg[dst[e]], 1);
}

__global__ void csr8init_kernel(int* __restrict__ c8a, int* __restrict__ c8b) {
    int i = blockIdx.x * blockDim.x + threadIdx.x;   // NN*JJ
    if (i < NN * JJ) { int n = i >> 3; c8a[i] = n; c8b[i] = n; }
}

__global__ void scan_kernel(const int* __restrict__ deg, int* __restrict__ off) {
    __shared__ int sm[1024];
    __shared__ int carry_s;
    if (threadIdx.x == 0) { carry_s = 0; off[0] = 0; }
    __syncthreads();
    for (int base = 0; base < NN; base += 1024) {
        int i = base + (int)threadIdx.x;
        int v = (i < NN) ? deg[i] : 0;
        sm[threadIdx.x] = v;
        __syncthreads();
        for (int s = 1; s < 1024; s <<= 1) {
            int t = (threadIdx.x >= (unsigned)s) ? sm[threadIdx.x - s] : 0;
            __syncthreads();
            sm[threadIdx.x] += t;
            __syncthreads();
        }
        if (i < NN) off[i + 1] = carry_s + sm[threadIdx.x];
        __syncthreads();
        if (threadIdx.x == 0) carry_s += sm[1023];
        __syncthreads();
    }
}

__global__ void fill_kernel(const int* __restrict__ src, const int* __restrict__ dst,
                            const int* __restrict__ off, int* __restrict__ cursor,
                            int* __restrict__ csr_src, int* __restrict__ csrP) {
    int e = blockIdx.x * blockDim.x + threadIdx.x;
    if (e < EE) {
        int d = dst[e];
        int p = atomicAdd(&cursor[d], 1);
        int s = src[e];
        csr_src[off[d] + p] = s;
        if (p < JJ) csrP[d * JJ + p] = s;
    }
}

// ---------------- precompute vl/vr for all 8 GATs ----------------
// vbuf layout: 8 slots of [vl(H*T=40) | vr(40)];
__global__ void vpre_kernel(const float* __restrict__ fc0, const float* __restrict__ al0, const float* __restrict__ ar0,
                            const float* __restrict__ fc1, const float* __restrict__ al1, const float* __restrict__ ar1,
                            const float* __restrict__ fc2, const float* __restrict__ al2, const float* __restrict__ ar2,
                            const float* __restrict__ fc3, const float* __restrict__ al3, const float* __restrict__ ar3,
                            float* __restrict__ vbuf) {
    int j = threadIdx.x;                 // 0..319
    if (j >= 320) return;
    int g = j / 40, r = j % 40;
    int h = r / 10, t = r % 10;
    int which = g & 3, layer = g >> 2;
    const float* fc; const float* al; const float* ar;
    if (which == 0)      { fc = fc0; al = al0; ar = ar0; }
    else if (which == 1) { fc = fc1; al = al1; ar = ar1; }
    else if (which == 2) { fc = fc2; al = al2; ar = ar2; }
    else                 { fc = fc3; al = al3; ar = ar3; }
    fc += layer * (HH * DD * TT);
    al += layer * (HH * DD);
    ar += layer * (HH * DD);
    float vl = 0.f, vr = 0.f;
#pragma unroll
    for (int d = 0; d < DD; d++) {
        float w = fc[(h * DD + d) * TT + t];
        vl += al[h * DD + d] * w;
        vr += ar[h * DD + d] * w;
    }
    vbuf[g * 80 + r] = vl;
    vbuf[g * 80 + 40 + r] = vr;
}

// ---------------- gat8: chain-flattened single-GAT pass ----------------
// r11: consolidated r1..r10 evidence says the wall is per-wave MLP on a
// dependent chain (r1 with 40+ loads in flight: 78 us/pass @2.2 TB/s; r6/r10
// with <=6: 130+ us for 1/4 the bytes). Fix: padded csrP[n][8] (sentinel =
// self) makes edge indices addressable from n alone -> round 1 loads {deg,
// off, idx int4 x2, self row} all independent; round 2 issues ALL 8 edge
// rows together (24 wide loads in flight). Serial depth = 2 memory rounds
// for 97.9% of nodes (Poisson-4); deg>8 overflows via real CSR (rare,
// wave-uniform branch). Live set ~120 (rows 80 + vl 10 + acc 10 + misc)
// fits the 128-VGPR tier -- the r2/r3 spills were live ~170.
// Wave layout: i=(nb<<2)|h -> 16 consecutive nb x 4 heads, one node/wave;
// edge row-sets are 768 B contiguous per 16-nb half-batch.
struct GatCfg {
    const float* f; const float* W; const float* v;
    const int* off; const int* csr; const int* csrP; const int* deg;
    float* g; float* stats;
};
struct GatCfg4 { GatCfg c[4]; };

#define LOAD_ROW(dst, q)                                        \
    {                                                           \
        float4 _r0 = *(const float4*)(q);                       \
        float4 _r1 = *(const float4*)((q) + 4);                 \
        float2 _r2 = *(const float2*)((q) + 8);                 \
        dst[0]=_r0.x; dst[1]=_r0.y; dst[2]=_r0.z; dst[3]=_r0.w; \
        dst[4]=_r1.x; dst[5]=_r1.y; dst[6]=_r1.z; dst[7]=_r1.w; \
        dst[8]=_r2.x; dst[9]=_r2.y;                             \
    }

template <bool STATS>
__global__ void __launch_bounds__(256)
gat8_kernel(GatCfg4 cfgs) {
    const GatCfg cfg = cfgs.c[blockIdx.y];
    __shared__ float sW[HH * DD * TT];      // 400
    __shared__ float sv[2 * HH * TT];       // 80: [vl(40) | vr(40)]
    for (int k = threadIdx.x; k < HH * DD * TT; k += blockDim.x) sW[k] = cfg.W[k];
    if (threadIdx.x < 2 * HH * TT) sv[threadIdx.x] = cfg.v[threadIdx.x];
    __syncthreads();

    const float* __restrict__ f = cfg.f;

    int i = blockIdx.x * blockDim.x + threadIdx.x;   // over NB*HH
    float lsum = 0.f, lsq = 0.f;
    if (i < NBH_T) {
        int h  = i & 3;
        int nb = i >> 2;          // n*32 + b
        int b  = nb & 31;
        int n  = nb >> 5;

        // ---- round 1: all independent loads issued together ----
        int dg   = cfg.deg[n];
        int off0 = cfg.off[n];
        int4 c0 = *(const int4*)(cfg.csrP + n * JJ);
        int4 c1 = *(const int4*)(cfg.csrP + n * JJ + 4);
        float fs[TT];
        LOAD_ROW(fs, f + (size_t)nb * FS);

        float vl[TT];
#pragma unroll
        for (int t = 0; t < TT; t++) vl[t] = sv[h * TT + t];
        float er = 0.f;
#pragma unroll
        for (int t = 0; t < TT; t++) er += sv[HH * TT + h * TT + t] * fs[t];

        // ---- round 2: all 8 edge rows in flight at once ----
        int cv[JJ] = { c0.x, c0.y, c0.z, c0.w, c1.x, c1.y, c1.z, c1.w };
        float rows[JJ][TT];
#pragma unroll
        for (int j = 0; j < JJ; j++) {
            const float* q = f + (size_t)(cv[j] * BB + b) * FS;
            LOAD_ROW(rows[j], q);
        }
        float wj[JJ];
#pragma unroll
        for (int j = 0; j < JJ; j++) {
            float el = 0.f;
#pragma unroll
            for (int t = 0; t < TT; t++) el += vl[t] * rows[j][t];
            float z = el + er; z = (z >= 0.f) ? z : NEG * z;
            float w = __expf(z);
            wj[j] = (j < dg) ? w : 0.f;
        }
        float den = 0.f;
        float acc[TT];
#pragma unroll
        for (int t = 0; t < TT; t++) acc[t] = 0.f;
#pragma unroll
        for (int j = 0; j < JJ; j++) {
            den += wj[j];
#pragma unroll
            for (int t = 0; t < TT; t++) acc[t] += wj[j] * rows[j][t];
        }

        // ---- overflow for deg > 8 (wave-uniform, ~2% of nodes) ----
        for (int k = off0 + JJ; k < off0 + dg; k++) {
            int s = cfg.csr[k];
            float fr[TT];
            LOAD_ROW(fr, f + (size_t)(s * BB + b) * FS);
            float el = 0.f;
#pragma unroll
            for (int t = 0; t < TT; t++) el += vl[t] * fr[t];
            float z = el + er; z = (z >= 0.f) ? z : NEG * z;
            float w = __expf(z);
            den += w;
#pragma unroll
            for (int t = 0; t < TT; t++) acc[t] += w * fr[t];
        }

        float rd = (dg > 0) ? (1.0f / den) : 0.f;

        // W_h on aggregated feat, leaky, mean over heads via shfl_xor
        float outv[DD];
#pragma unroll
        for (int d = 0; d < DD; d++) {
            float va = 0.f;
#pragma unroll
            for (int t = 0; t < TT; t++) va += sW[(h * DD + d) * TT + t] * acc[t];
            va *= rd;
            va = (va >= 0.f) ? va : NEG * va;
            outv[d] = va * 0.25f;
        }
#pragma unroll
        for (int d = 0; d < DD; d++) {
            outv[d] += __shfl_xor(outv[d], 1, 64);
            outv[d] += __shfl_xor(outv[d], 2, 64);
        }
        if (h == 0) {
            float* gp = cfg.g + (size_t)nb * DD;
#pragma unroll
            for (int d = 0; d < DD; d++) {
                float o = outv[d];
                gp[d] = o;
                if (STATS) { lsum += o; lsq += o * o; }
            }
        }
    }
    if (STATS) {
#pragma unroll
        for (int o = 32; o > 0; o >>= 1) {
            lsum += __shfl_down(lsum, o, 64);
            lsq  += __shfl_down(lsq, o, 64);
        }
        __shared__ float ss[4][2];
        int wid = threadIdx.x >> 6, lid = threadIdx.x & 63;
        if (lid == 0) { ss[wid][0] = lsum; ss[wid][1] = lsq; }
        __syncthreads();
        if (threadIdx.x == 0) {
            float a0 = 0.f, a1 = 0.f;
#pragma unroll
            for (int w = 0; w < 4; w++) { a0 += ss[w][0]; a1 += ss[w][1]; }
            atomicAdd(&cfg.stats[0], a0);
            atomicAdd(&cfg.stats[1], a1);
        }
    }
}

// ---------------- LN(A), LN(B), average; writes padded feat rows ----------
__global__ void lncomb_kernel(const float* __restrict__ ga, const float* __restrict__ gb,
                              const float* __restrict__ stats, float* __restrict__ h) {
    int i = blockIdx.x * blockDim.x + threadIdx.x;
    if (i >= NBT) return;
    const float M = (float)NBT;
    float ma = stats[0] / M; float va = stats[1] / M - ma * ma;
    float mb = stats[2] / M; float vb = stats[3] / M - mb * mb;
    float ra = rsqrtf(va + 1e-5f), rb = rsqrtf(vb + 1e-5f);
    int nb = i / DD, t = i - nb * DD;
    h[(size_t)nb * FS + t] = 0.5f * ((ga[i] - ma) * ra + (gb[i] - mb) * rb);
}

// ---------------- final combine ----------------
__global__ void outcomb_kernel(const float* __restrict__ reg, const float* __restrict__ ga,
                               const float* __restrict__ gb, float* __restrict__ out) {
    int i = blockIdx.x * blockDim.x + threadIdx.x;
    if (i >= NBT) return;
    int nb = i / DD;
    out[i] = (reg[nb] + ga[i] + gb[i]) * (1.0f / 3.0f);
}

extern "C" void kernel_launch(void* const* d_in, const int* in_sizes, int n_in,
                              void* d_out, int out_size, void* d_ws, size_t ws_size,
                              hipStream_t stream) {
    const float* x      = (const float*)d_in[0];
    const int* ps_src   = (const int*)d_in[1];
    const int* ps_dst   = (const int*)d_in[2];
    const int* rl_src   = (const int*)d_in[3];
    const int* rl_dst   = (const int*)d_in[4];
    const float* mu_p_fc = (const float*)d_in[5];
    const float* mu_p_al = (const float*)d_in[6];
    const float* mu_p_ar = (const float*)d_in[7];
    const float* sg_p_fc = (const float*)d_in[8];
    const float* sg_p_al = (const float*)d_in[9];
    const float* sg_p_ar = (const float*)d_in[10];
    const float* mu_r_fc = (const float*)d_in[11];
    const float* mu_r_al = (const float*)d_in[12];
    const float* mu_r_ar = (const float*)d_in[13];
    const float* sg_r_fc = (const float*)d_in[14];
    const float* sg_r_al = (const float*)d_in[15];
    const float* sg_r_ar = (const float*)d_in[16];
    const float* reg_mu_w = (const float*)d_in[17];
    const float* reg_mu_b = (const float*)d_in[18];
    const float* reg_sg_w = (const float*)d_in[19];
    const float* reg_sg_b = (const float*)d_in[20];

    float* out = (float*)d_out;

    // ---- workspace carve ----
    float* fw = (float*)d_ws;
    float* mu    = fw;              fw += NBF;   // padded stride-12 feats
    float* sigma = fw;              fw += NBF;
    float* hp    = fw;              fw += NBF;
    float* hrl   = fw;              fw += NBF;
    float* gA    = fw;              fw += NBT;   // stride-10 GAT outputs
    float* gB    = fw;              fw += NBT;
    float* gA2   = fw;              fw += NBT;
    float* gB2   = fw;              fw += NBT;
    float* regmu = fw;              fw += NB;
    float* regsg = fw;              fw += NB;
    float* vbuf  = fw;              fw += 8 * 80;
    int* iw = (int*)fw;
    int* ps_off = iw;               iw += NN + 1;
    int* rl_off = iw;               iw += NN + 1;
    int* ps_csr = iw;               iw += EE;
    int* rl_csr = iw;               iw += EE;
    int* ps_c8  = iw;               iw += NN * JJ;
    int* rl_c8  = iw;               iw += NN * JJ;
    // zero region starts here:
    int* deg_ps = iw;               iw += NN;
    int* cur_ps = iw;               iw += NN;
    int* deg_rl = iw;               iw += NN;
    int* cur_rl = iw;               iw += NN;
    float* stats = (float*)iw;      // 8 floats
    size_t zero_bytes = (size_t)(4 * NN) * sizeof(int) + 8 * sizeof(float);
    hipMemsetAsync(deg_ps, 0, zero_bytes, stream);

    const int TPB = 256;
    const int GRID_NB  = (NB + TPB - 1) / TPB;
    const int GRID_NBH = (NBH_T + TPB - 1) / TPB;   // 5000
    const int GRID_NBT = (NBT + TPB - 1) / TPB;
    const int GRID_E   = (EE + TPB - 1) / TPB;
    const int GRID_C8  = (NN * JJ + TPB - 1) / TPB;

    extract_kernel<<<GRID_NB, TPB, 0, stream>>>(x, reg_mu_w, reg_mu_b, reg_sg_w, reg_sg_b,
                                                mu, sigma, regmu, regsg);

    // CSR (+padded csrP) for both graphs
    deg_kernel<<<GRID_E, TPB, 0, stream>>>(ps_dst, deg_ps);
    deg_kernel<<<GRID_E, TPB, 0, stream>>>(rl_dst, deg_rl);
    csr8init_kernel<<<GRID_C8, TPB, 0, stream>>>(ps_c8, rl_c8);
    scan_kernel<<<1, 1024, 0, stream>>>(deg_ps, ps_off);
    scan_kernel<<<1, 1024, 0, stream>>>(deg_rl, rl_off);
    fill_kernel<<<GRID_E, TPB, 0, stream>>>(ps_src, ps_dst, ps_off, cur_ps, ps_csr, ps_c8);
    fill_kernel<<<GRID_E, TPB, 0, stream>>>(rl_src, rl_dst, rl_off, cur_rl, rl_csr, rl_c8);

    // vl/vr precompute for all 8 GAT slots
    vpre_kernel<<<1, 320, 0, stream>>>(mu_p_fc, mu_p_al, mu_p_ar,
                                       sg_p_fc, sg_p_al, sg_p_ar,
                                       mu_r_fc, mu_r_al, mu_r_ar,
                                       sg_r_fc, sg_r_al, sg_r_ar, vbuf);

    // slots: 0 mu_p L0, 1 sg_p L0, 2 mu_r L0, 3 sg_r L0, 4 mu_p L1, 5 sg_p L1, 6 mu_r L1, 7 sg_r L1
    // ---- layer 0: 4 GAT passes, one dispatch (grid.y=4) ----
    {
        GatCfg4 c;
        c.c[0] = { mu,    mu_p_fc, vbuf + 0 * 80, ps_off, ps_csr, ps_c8, deg_ps, gA,  stats + 0 };
        c.c[1] = { sigma, sg_p_fc, vbuf + 1 * 80, ps_off, ps_csr, ps_c8, deg_ps, gB,  stats + 2 };
        c.c[2] = { mu,    mu_r_fc, vbuf + 2 * 80, rl_off, rl_csr, rl_c8, deg_rl, gA2, stats + 4 };
        c.c[3] = { sigma, sg_r_fc, vbuf + 3 * 80, rl_off, rl_csr, rl_c8, deg_rl, gB2, stats + 6 };
        dim3 grid(GRID_NBH, 4, 1);
        gat8_kernel<true><<<grid, TPB, 0, stream>>>(c);
    }
    lncomb_kernel<<<GRID_NBT, TPB, 0, stream>>>(gA, gB, stats + 0, hp);
    lncomb_kernel<<<GRID_NBT, TPB, 0, stream>>>(gA2, gB2, stats + 4, hrl);

    // ---- final layers: 4 GAT passes, one dispatch ----
    {
        GatCfg4 c;
        c.c[0] = { hp,  mu_p_fc + 400, vbuf + 4 * 80, ps_off, ps_csr, ps_c8, deg_ps, gA,  nullptr };
        c.c[1] = { hp,  sg_p_fc + 400, vbuf + 5 * 80, ps_off, ps_csr, ps_c8, deg_ps, gB,  nullptr };
        c.c[2] = { hrl, mu_r_fc + 400, vbuf + 6 * 80, rl_off, rl_csr, rl_c8, deg_rl, gA2, nullptr };
        c.c[3] = { hrl, sg_r_fc + 400, vbuf + 7 * 80, rl_off, rl_csr, rl_c8, deg_rl, gB2, nullptr };
        dim3 grid(GRID_NBH, 4, 1);
        gat8_kernel<false><<<grid, TPB, 0, stream>>>(c);
    }

    outcomb_kernel<<<GRID_NBT, TPB, 0, stream>>>(regmu, gA, gA2, out);
    outcomb_kernel<<<GRID_NBT, TPB, 0, stream>>>(regsg, gB, gB2, out + NBT);
}